// Round 8
// baseline (419.049 us; speedup 1.0000x reference)
//
#include <hip/hip_runtime.h>
#include <hip/hip_bf16.h>
#include <math.h>

// Problem constants (from reference)
#define BB 64
#define LL 512
#define CC 256
#define HH 8
#define DHH 32
#define NN (BB * LL)

typedef __attribute__((ext_vector_type(8))) short bf16x8;   // MFMA A/B frag
typedef __attribute__((ext_vector_type(4))) float f32x4;    // MFMA C/D frag
typedef __attribute__((ext_vector_type(4))) unsigned short us4;

#define MFMA16(a, b, c) __builtin_amdgcn_mfma_f32_16x16x32_bf16(a, b, c, 0, 0, 0)

__device__ __forceinline__ unsigned short f2bf(float f) {
  unsigned u = __builtin_bit_cast(unsigned, f);
  u += 0x7fffu + ((u >> 16) & 1u);  // RNE
  return (unsigned short)(u >> 16);
}
__device__ __forceinline__ float bf2f(unsigned short h) {
  unsigned u = ((unsigned)h) << 16;
  return __builtin_bit_cast(float, u);
}

// ---------------------------------------------------------------------------
// K0: weight-only conversions (x->bf16 lives in k_scorer).
// ---------------------------------------------------------------------------
__global__ __launch_bounds__(256) void k_cvt(
    const float* __restrict__ Ws1, unsigned short* __restrict__ W1h,
    unsigned short* __restrict__ W1l, const float* __restrict__ Win,
    unsigned short* __restrict__ Winh, const float* __restrict__ Wout,
    unsigned short* __restrict__ Wouth, const float* __restrict__ Wm1,
    unsigned short* __restrict__ Wm1h, const float* __restrict__ Wm2,
    unsigned short* __restrict__ Wm2h) {
  const int NW1 = CC * CC;
  const int NWIN = 3 * CC * CC;
  const int NWM = 2 * CC * CC;
  int i = blockIdx.x * 256 + threadIdx.x;
  if (i < NW1) {
    float v = Ws1[i];
    unsigned short hb = f2bf(v);
    W1h[i] = hb;
    W1l[i] = f2bf(v - bf2f(hb));
    return;
  }
  i -= NW1;
  if (i < NWIN) { Winh[i] = f2bf(Win[i]); return; }
  i -= NWIN;
  if (i < NW1) { Wouth[i] = f2bf(Wout[i]); return; }
  i -= NW1;
  if (i < NWM) { Wm1h[i] = f2bf(Wm1[i]); return; }
  i -= NWM;
  if (i < NWM) Wm2h[i] = f2bf(Wm2[i]);
}

// ---------------------------------------------------------------------------
// K1: scorer via split-bf16 MFMA; emits xh as side effect (unchanged).
// ---------------------------------------------------------------------------
__global__ __launch_bounds__(256) void k_scorer(
    const float* __restrict__ x, unsigned short* __restrict__ xh,
    const unsigned short* __restrict__ W1h,
    const unsigned short* __restrict__ W1l, const float* __restrict__ bs1,
    const float* __restrict__ Ws2, const float* __restrict__ bs2,
    float* __restrict__ scores) {
  __shared__ unsigned short Ah[32][264];
  __shared__ unsigned short Al[32][264];
  __shared__ float red[4][32];
  int t = threadIdx.x;
  int tok0 = blockIdx.x * 32;
  for (int idx = t; idx < 32 * 64; idx += 256) {
    int r = idx >> 6, c4 = idx & 63;
    float4 v = *(const float4*)(x + (size_t)(tok0 + r) * CC + c4 * 4);
    float vv[4] = {v.x, v.y, v.z, v.w};
    unsigned short hb[4], lb[4];
#pragma unroll
    for (int j = 0; j < 4; ++j) {
      hb[j] = f2bf(vv[j]);
      lb[j] = f2bf(vv[j] - bf2f(hb[j]));
    }
    *(us4*)&Ah[r][c4 * 4] = *(us4*)hb;
    *(us4*)&Al[r][c4 * 4] = *(us4*)lb;
    ((us4*)(xh + (size_t)(tok0 + r) * CC))[c4] = *(us4*)hb;  // side output
  }
  __syncthreads();
  int lane = t & 63, wid = t >> 6, quad = lane >> 4, l16 = lane & 15;
  f32x4 acc[2][4] = {};
  for (int k0 = 0; k0 < CC; k0 += 32) {
    bf16x8 a0h = *(const bf16x8*)&Ah[l16][k0 + quad * 8];
    bf16x8 a1h = *(const bf16x8*)&Ah[16 + l16][k0 + quad * 8];
    bf16x8 a0l = *(const bf16x8*)&Al[l16][k0 + quad * 8];
    bf16x8 a1l = *(const bf16x8*)&Al[16 + l16][k0 + quad * 8];
#pragma unroll
    for (int nt = 0; nt < 4; ++nt) {
      int n = wid * 64 + nt * 16 + l16;
      bf16x8 bh = *(const bf16x8*)&W1h[(size_t)n * CC + k0 + quad * 8];
      bf16x8 bl = *(const bf16x8*)&W1l[(size_t)n * CC + k0 + quad * 8];
      acc[0][nt] = MFMA16(a0h, bh, acc[0][nt]);
      acc[0][nt] = MFMA16(a0h, bl, acc[0][nt]);
      acc[0][nt] = MFMA16(a0l, bh, acc[0][nt]);
      acc[1][nt] = MFMA16(a1h, bh, acc[1][nt]);
      acc[1][nt] = MFMA16(a1h, bl, acc[1][nt]);
      acc[1][nt] = MFMA16(a1l, bh, acc[1][nt]);
    }
  }
  float rs[2][4] = {};
#pragma unroll
  for (int nt = 0; nt < 4; ++nt) {
    int n = wid * 64 + nt * 16 + l16;
    float b1 = bs1[n], w2 = Ws2[n];
#pragma unroll
    for (int rt = 0; rt < 2; ++rt)
#pragma unroll
      for (int r = 0; r < 4; ++r)
        rs[rt][r] += fmaxf(acc[rt][nt][r] + b1, 0.f) * w2;
  }
#pragma unroll
  for (int o = 1; o < 16; o <<= 1)
#pragma unroll
    for (int rt = 0; rt < 2; ++rt)
#pragma unroll
      for (int r = 0; r < 4; ++r) rs[rt][r] += __shfl_xor(rs[rt][r], o);
  if (l16 == 0) {
#pragma unroll
    for (int rt = 0; rt < 2; ++rt)
#pragma unroll
      for (int r = 0; r < 4; ++r)
        red[wid][rt * 16 + quad * 4 + r] = rs[rt][r];
  }
  __syncthreads();
  if (t < 32)
    scores[tok0 + t] = red[0][t] + red[1][t] + red[2][t] + red[3][t] + bs2[0];
}

// ---------------------------------------------------------------------------
// K2: fused kper + log_softmax+gumbel + selection (unchanged).
// ---------------------------------------------------------------------------
__global__ __launch_bounds__(512) void k_presel(
    const float* __restrict__ scores, const float* __restrict__ gumbel,
    const float* __restrict__ ratio, int* __restrict__ k_per,
    int* __restrict__ codes, int* __restrict__ row2l) {
  __shared__ float zs[LL];
  __shared__ int sel[LL];
  __shared__ float red[8];
  __shared__ int kps[64];
  int b = blockIdx.x, l = threadIdx.x;
  int lane = l & 63, wid = l >> 6;
  if (l < 64) {
    int kp_ = (int)ceilf(ratio[l] * (float)LL);
    kp_ = min(max(kp_, 1), LL);
    kps[l] = kp_;
    if (l == b) k_per[b] = kp_;
  }
  __syncthreads();
  int kp = kps[b];
  int km = 0;
#pragma unroll
  for (int j = 0; j < 64; ++j) km = max(km, kps[j]);
  float v = scores[b * LL + l];
  float m = v;
  for (int o = 32; o > 0; o >>= 1) m = fmaxf(m, __shfl_down(m, o));
  if (lane == 0) red[wid] = m;
  __syncthreads();
  m = red[0];
#pragma unroll
  for (int j = 1; j < 8; ++j) m = fmaxf(m, red[j]);
  __syncthreads();
  float e = expf(v - m);
  for (int o = 32; o > 0; o >>= 1) e += __shfl_down(e, o);
  if (lane == 0) red[wid] = e;
  __syncthreads();
  float tot = red[0];
#pragma unroll
  for (int j = 1; j < 8; ++j) tot += red[j];
  float lse = m + logf(tot);
  float zl = v - lse + gumbel[b * LL + l];
  zs[l] = zl;
  __syncthreads();
  int rank = 0;
  for (int j = 0; j < LL; ++j) {
    float zj = zs[j];
    rank += (zj > zl) || (zj == zl && j < l);
  }
  int s = (rank < km) ? 1 : 0;
  sel[l] = s;
  __syncthreads();
  int ps = 0;
  for (int j = 0; j < l; ++j) ps += sel[j];
  int kept = s && (ps < kp);
  int keptPrefix = min(ps, kp);
  int code;
  if (kept)
    code = ps;
  else if ((l - keptPrefix) < (km - kp))
    code = kp;
  else
    code = -1;
  codes[b * LL + l] = code;
  if (kept) row2l[b * LL + ps] = l;
}

// ---------------------------------------------------------------------------
// K4 v3: qkv in-proj via bf16 MFMA; outputs now staged through LDS (3 rounds
// q/k/v) -> cooperative us4 row stores (512B segments) instead of 2B scatter.
// ---------------------------------------------------------------------------
__global__ __launch_bounds__(256) void k_qkv(
    const unsigned short* __restrict__ xh, const int* __restrict__ row2l,
    const int* __restrict__ k_per, const unsigned short* __restrict__ Winh,
    const float* __restrict__ b_in, unsigned short* __restrict__ qh,
    unsigned short* __restrict__ kh, unsigned short* __restrict__ vh) {
  int b = blockIdx.y;
  int kp = k_per[b];
  int rows = (kp < LL) ? kp + 1 : LL;
  int r0 = blockIdx.x * 32;
  if (r0 >= rows) return;
  __shared__ unsigned short A1[32][264];
  int t = threadIdx.x;
  for (int idx = t; idx < 32 * 64; idx += 256) {
    int r = idx >> 6, c4 = idx & 63;
    int gr = r0 + r;
    us4 v = {0, 0, 0, 0};
    if (gr < kp) {
      int l = row2l[b * LL + gr];
      v = ((const us4*)(xh + ((size_t)b * LL + l) * CC))[c4];
    }
    *(us4*)&A1[r][c4 * 4] = v;
  }
  __syncthreads();
  int lane = t & 63, wid = t >> 6, quad = lane >> 4, row16 = lane & 15;
  f32x4 acc[2][12] = {};
  for (int k0 = 0; k0 < CC; k0 += 32) {
    bf16x8 a0 = *(const bf16x8*)&A1[row16][k0 + quad * 8];
    bf16x8 a1 = *(const bf16x8*)&A1[16 + row16][k0 + quad * 8];
#pragma unroll
    for (int nt = 0; nt < 12; ++nt) {
      int n = wid * 192 + nt * 16 + row16;
      bf16x8 bfr = *(const bf16x8*)&Winh[(size_t)n * CC + k0 + quad * 8];
      acc[0][nt] = MFMA16(a0, bfr, acc[0][nt]);
      acc[1][nt] = MFMA16(a1, bfr, acc[1][nt]);
    }
  }
  // 3 rounds: scatter into A1 (LDS), cooperative row store to q/k/v
#pragma unroll
  for (int w = 0; w < 3; ++w) {
    __syncthreads();  // previous readers of A1 done
#pragma unroll
    for (int nt = 0; nt < 12; ++nt) {
      int n = wid * 192 + nt * 16 + row16;
      if ((n >> 8) == w) {
        int nc = n & 255;
        float bias = b_in[n];
#pragma unroll
        for (int rt = 0; rt < 2; ++rt)
#pragma unroll
          for (int r = 0; r < 4; ++r)
            A1[rt * 16 + quad * 4 + r][nc] = f2bf(acc[rt][nt][r] + bias);
      }
    }
    __syncthreads();
    unsigned short* dst = (w == 0) ? qh : (w == 1) ? kh : vh;
    for (int idx = t; idx < 32 * 64; idx += 256) {
      int r = idx >> 6, c4 = idx & 63;
      int row = r0 + r;
      if (row < rows)
        ((us4*)(dst + ((size_t)b * LL + row) * CC))[c4] = *(us4*)&A1[r][c4 * 4];
    }
  }
}

// ---------------------------------------------------------------------------
// K6: flash attention, 128-query blocks (unchanged from R6).
// ---------------------------------------------------------------------------
__global__ __launch_bounds__(256, 4) void k_attn(
    const unsigned short* __restrict__ qh, const unsigned short* __restrict__ kh,
    const unsigned short* __restrict__ vh, const int* __restrict__ k_per,
    unsigned short* __restrict__ ah) {
  int h = blockIdx.y, b = blockIdx.z;
  int kp = k_per[b];
  int rows = (kp < LL) ? kp + 1 : LL;
  int q0 = blockIdx.x * 128;
  if (q0 >= rows) return;
  int t = threadIdx.x;
  int lane = t & 63, wid = t >> 6, quad = lane >> 4, l16 = lane & 15;

  __shared__ unsigned short Kc[128 * 40];
  __shared__ unsigned short Vt[32 * 132];
  __shared__ unsigned short Pb[4][16 * 132];

  size_t base = ((size_t)b * LL) * CC + (size_t)h * DHH;

  bf16x8 aQ[2] = {};
  float m[2][4], l[2][4];
  f32x4 o0[2] = {}, o1[2] = {};
#pragma unroll
  for (int g = 0; g < 2; ++g) {
    int myq = q0 + wid * 32 + g * 16 + l16;
    if (myq < rows)
      aQ[g] = *(const bf16x8*)(qh + base + (size_t)myq * CC + quad * 8);
#pragma unroll
    for (int r = 0; r < 4; ++r) { m[g][r] = -1e30f; l[g][r] = 0.f; }
  }
  const float scale = 0.17677669529663687f;  // 1/sqrt(32)
  int nch = (kp + 127) >> 7;
  unsigned short* Pw = Pb[wid];

  for (int c = 0; c < nch; ++c) {
    int kbase = c << 7;
    __syncthreads();
    for (int idx = t; idx < 1024; idx += 256) {
      int key = idx >> 3, c4 = idx & 7;
      int gk = kbase + key;
      us4 kv = {0, 0, 0, 0}, vv = {0, 0, 0, 0};
      if (gk < kp) {
        kv = *(const us4*)(kh + base + (size_t)gk * CC + c4 * 4);
        vv = *(const us4*)(vh + base + (size_t)gk * CC + c4 * 4);
      }
      *(us4*)&Kc[key * 40 + c4 * 4] = kv;
#pragma unroll
      for (int j = 0; j < 4; ++j) Vt[(c4 * 4 + j) * 132 + key] = vv[j];
    }
    __syncthreads();
#pragma unroll
    for (int g = 0; g < 2; ++g) {
      f32x4 s[8];
#pragma unroll
      for (int tt = 0; tt < 8; ++tt) {
        f32x4 z4 = {};
        bf16x8 bK = *(const bf16x8*)&Kc[(tt * 16 + l16) * 40 + quad * 8];
        s[tt] = MFMA16(aQ[g], bK, z4);
      }
      float cm[4] = {-1e30f, -1e30f, -1e30f, -1e30f};
#pragma unroll
      for (int tt = 0; tt < 8; ++tt) {
        float sb = (kbase + tt * 16 + l16 < kp) ? 0.f : -1e30f;
#pragma unroll
        for (int r = 0; r < 4; ++r) {
          float v = fmaf(s[tt][r], scale, sb);
          s[tt][r] = v;
          cm[r] = fmaxf(cm[r], v);
        }
      }
#pragma unroll
      for (int o = 1; o < 16; o <<= 1)
#pragma unroll
        for (int r = 0; r < 4; ++r) cm[r] = fmaxf(cm[r], __shfl_xor(cm[r], o));
      float alpha[4], cs[4] = {0.f, 0.f, 0.f, 0.f};
#pragma unroll
      for (int r = 0; r < 4; ++r) {
        float mn = fmaxf(m[g][r], cm[r]);
        alpha[r] = __expf(m[g][r] - mn);
        m[g][r] = mn;
      }
#pragma unroll
      for (int tt = 0; tt < 8; ++tt)
#pragma unroll
        for (int r = 0; r < 4; ++r) {
          float p = __expf(s[tt][r] - m[g][r]);
          s[tt][r] = p;
          cs[r] += p;
        }
#pragma unroll
      for (int o = 1; o < 16; o <<= 1)
#pragma unroll
        for (int r = 0; r < 4; ++r) cs[r] += __shfl_xor(cs[r], o);
#pragma unroll
      for (int r = 0; r < 4; ++r) {
        l[g][r] = l[g][r] * alpha[r] + cs[r];
        o0[g][r] *= alpha[r];
        o1[g][r] *= alpha[r];
      }
#pragma unroll
      for (int tt = 0; tt < 8; ++tt)
#pragma unroll
        for (int r = 0; r < 4; ++r)
          Pw[(quad * 4 + r) * 132 + tt * 16 + l16] = f2bf(s[tt][r]);
#pragma unroll
      for (int gg = 0; gg < 4; ++gg) {
        if (kbase + gg * 32 < kp) {
          bf16x8 aP = *(const bf16x8*)&Pw[l16 * 132 + gg * 32 + quad * 8];
          int koff = gg * 32 + quad * 8;
          struct U8 { us4 a, bq; };
          U8 u0, u1;
          u0.a = *(const us4*)&Vt[l16 * 132 + koff];
          u0.bq = *(const us4*)&Vt[l16 * 132 + koff + 4];
          u1.a = *(const us4*)&Vt[(16 + l16) * 132 + koff];
          u1.bq = *(const us4*)&Vt[(16 + l16) * 132 + koff + 4];
          o0[g] = MFMA16(aP, __builtin_bit_cast(bf16x8, u0), o0[g]);
          o1[g] = MFMA16(aP, __builtin_bit_cast(bf16x8, u1), o1[g]);
        }
      }
    }
  }
#pragma unroll
  for (int g = 0; g < 2; ++g)
#pragma unroll
    for (int r = 0; r < 4; ++r) {
      int q = q0 + wid * 32 + g * 16 + quad * 4 + r;
      if (q < rows) {
        float invl = 1.f / l[g][r];
        ah[base + (size_t)q * CC + l16] = f2bf(o0[g][r] * invl);
        ah[base + (size_t)q * CC + 16 + l16] = f2bf(o1[g][r] * invl);
      }
    }
}

// ---------------------------------------------------------------------------
// K7 v5: fused out-proj + residual + MLP. xh residual staged via LDS
// (coalesced), final out staged via LDS fp32 (pitch 260, 2-way-free) and
// written with cooperative float4 (1KB/row). LDS ~34 KB -> 4 blocks/CU.
// ---------------------------------------------------------------------------
__global__ __launch_bounds__(256, 4) void k_opmlp(
    const unsigned short* __restrict__ ah, const int* __restrict__ codes,
    const unsigned short* __restrict__ Wouth, const float* __restrict__ bout,
    const unsigned short* __restrict__ xh, const float* __restrict__ ratio,
    const unsigned short* __restrict__ Wm1h, const float* __restrict__ bm1,
    const unsigned short* __restrict__ Wm2h, const float* __restrict__ bm2,
    float* __restrict__ out) {
  __shared__ __align__(16) unsigned char smem[16896 * 2];  // 33792 B
  unsigned short (*A1)[264] = (unsigned short (*)[264])smem;
  unsigned short (*Hs)[264] = (unsigned short (*)[264])(smem + 16896);
  float (*Ob)[260] = (float (*)[260])smem;  // 32*260*4 = 33280 <= 33792
  __shared__ int cd[32];
  int b = blockIdx.y;
  int l0 = blockIdx.x * 32;
  int t = threadIdx.x;
  if (t < 32) cd[t] = codes[b * LL + l0 + t];
  __syncthreads();
  // gather attn rows -> A1; stage xh residual tile -> Hs (both coalesced)
  for (int idx = t; idx < 32 * 64; idx += 256) {
    int r = idx >> 6, c4 = idx & 63;
    int c = cd[r];
    us4 v = {0, 0, 0, 0};
    if (c >= 0) v = ((const us4*)(ah + ((size_t)b * LL + c) * CC))[c4];
    *(us4*)&A1[r][c4 * 4] = v;
    *(us4*)&Hs[r][c4 * 4] = ((const us4*)(xh + ((size_t)b * LL + l0 + r) * CC))[c4];
  }
  __syncthreads();
  int lane = t & 63, wid = t >> 6, quad = lane >> 4, l16 = lane & 15;

  // ---- phase A: out-proj GEMM (wave owns cols wid*64..+63) ----
  f32x4 acc[2][4] = {};
  for (int k0 = 0; k0 < CC; k0 += 32) {
    bf16x8 a0 = *(const bf16x8*)&A1[l16][k0 + quad * 8];
    bf16x8 a1 = *(const bf16x8*)&A1[16 + l16][k0 + quad * 8];
#pragma unroll
    for (int nt = 0; nt < 4; ++nt) {
      int n = wid * 64 + nt * 16 + l16;
      bf16x8 bfr = *(const bf16x8*)&Wouth[(size_t)n * CC + k0 + quad * 8];
      acc[0][nt] = MFMA16(a0, bfr, acc[0][nt]);
      acc[1][nt] = MFMA16(a1, bfr, acc[1][nt]);
    }
  }
  float res[2][4][4];
  float rt_ratio = ratio[b];
#pragma unroll
  for (int rt = 0; rt < 2; ++rt) {
#pragma unroll
    for (int nt = 0; nt < 4; ++nt) {
      int n = wid * 64 + nt * 16 + l16;
      float bias = bout[n];
#pragma unroll
      for (int r = 0; r < 4; ++r) {
        int rl = rt * 16 + quad * 4 + r;
        int c = cd[rl];
        float y = (c >= 0) ? (acc[rt][nt][r] + bias) : 0.f;
        res[rt][nt][r] = (y + bf2f(Hs[rl][n])) * rt_ratio;
      }
    }
  }
  __syncthreads();  // A1 (and Hs residual) reads done -> safe to overwrite
#pragma unroll
  for (int rt = 0; rt < 2; ++rt)
#pragma unroll
    for (int nt = 0; nt < 4; ++nt) {
      int n = wid * 64 + nt * 16 + l16;
#pragma unroll
      for (int r = 0; r < 4; ++r)
        A1[rt * 16 + quad * 4 + r][n] = f2bf(res[rt][nt][r]);
    }
  __syncthreads();

  // ---- phase B: K-interleaved MLP ----
  f32x4 acc2[2][4] = {};
#pragma unroll
  for (int half = 0; half < 2; ++half) {
    f32x4 acc1[2][4] = {};
    for (int k0 = 0; k0 < CC; k0 += 32) {
      bf16x8 a0 = *(const bf16x8*)&A1[l16][k0 + quad * 8];
      bf16x8 a1 = *(const bf16x8*)&A1[16 + l16][k0 + quad * 8];
#pragma unroll
      for (int nt = 0; nt < 4; ++nt) {
        int nh = half * 256 + wid * 64 + nt * 16 + l16;
        bf16x8 bfr = *(const bf16x8*)&Wm1h[(size_t)nh * CC + k0 + quad * 8];
        acc1[0][nt] = MFMA16(a0, bfr, acc1[0][nt]);
        acc1[1][nt] = MFMA16(a1, bfr, acc1[1][nt]);
      }
    }
    __syncthreads();  // prior Hs readers (xh epilogue / GEMM2-half0) done
#pragma unroll
    for (int rt = 0; rt < 2; ++rt)
#pragma unroll
      for (int nt = 0; nt < 4; ++nt) {
        int nh = half * 256 + wid * 64 + nt * 16 + l16;
        int hc = nh - half * 256;
        float bias = bm1[nh];
#pragma unroll
        for (int r = 0; r < 4; ++r) {
          float v = fmaxf(acc1[rt][nt][r] + bias, 0.f);
          Hs[rt * 16 + quad * 4 + r][hc] = f2bf(v);
        }
      }
    __syncthreads();
    for (int k0 = 0; k0 < CC; k0 += 32) {
      bf16x8 a0 = *(const bf16x8*)&Hs[l16][k0 + quad * 8];
      bf16x8 a1 = *(const bf16x8*)&Hs[16 + l16][k0 + quad * 8];
#pragma unroll
      for (int nt = 0; nt < 4; ++nt) {
        int n = wid * 64 + nt * 16 + l16;
        bf16x8 bfr =
            *(const bf16x8*)&Wm2h[(size_t)n * (2 * CC) + half * 256 + k0 + quad * 8];
        acc2[0][nt] = MFMA16(a0, bfr, acc2[0][nt]);
        acc2[1][nt] = MFMA16(a1, bfr, acc2[1][nt]);
      }
    }
  }
  __syncthreads();  // all A1/Hs reads done -> reuse as fp32 out buffer
#pragma unroll
  for (int rt = 0; rt < 2; ++rt) {
#pragma unroll
    for (int nt = 0; nt < 4; ++nt) {
      int n = wid * 64 + nt * 16 + l16;
      float bias = bm2[n];
#pragma unroll
      for (int r = 0; r < 4; ++r) {
        int rl = rt * 16 + quad * 4 + r;
        Ob[rl][n] = res[rt][nt][r] + acc2[rt][nt][r] + bias;
      }
    }
  }
  __syncthreads();
  for (int idx = t; idx < 32 * 64; idx += 256) {
    int r = idx >> 6, c4 = idx & 63;
    *(float4*)(out + ((size_t)b * LL + l0 + r) * CC + c4 * 4) =
        *(const float4*)&Ob[r][c4 * 4];
  }
}

// ---------------------------------------------------------------------------
extern "C" void kernel_launch(void* const* d_in, const int* in_sizes, int n_in,
                              void* d_out, int out_size, void* d_ws,
                              size_t ws_size, hipStream_t stream) {
  (void)in_sizes; (void)n_in; (void)out_size; (void)ws_size;
  const float* x     = (const float*)d_in[0];
  const float* ratio = (const float*)d_in[3];
  const float* gum   = (const float*)d_in[4];
  const float* Ws1   = (const float*)d_in[5];
  const float* bs1   = (const float*)d_in[6];
  const float* Ws2   = (const float*)d_in[7];
  const float* bs2   = (const float*)d_in[8];
  const float* Win   = (const float*)d_in[9];
  const float* b_in  = (const float*)d_in[10];
  const float* Wout  = (const float*)d_in[11];
  const float* bout  = (const float*)d_in[12];
  const float* Wm1   = (const float*)d_in[13];
  const float* bm1   = (const float*)d_in[14];
  const float* Wm2   = (const float*)d_in[15];
  const float* bm2   = (const float*)d_in[16];
  float* out = (float*)d_out;

  // workspace layout
  const size_t NXC = (size_t)NN * CC;  // 8388608
  float* z    = (float*)d_ws;                     // N f32 (scores)
  int* k_per  = (int*)(z + NN);                   // 128 ints
  int* codes  = k_per + 128;                      // N ints
  int* row2l  = codes + NN;                       // N ints
  unsigned short* xh    = (unsigned short*)(row2l + NN);  // N*C bf16
  unsigned short* qh    = xh + NXC;
  unsigned short* kh    = qh + NXC;
  unsigned short* vh    = kh + NXC;
  unsigned short* ahb   = vh + NXC;
  unsigned short* Winh  = ahb + NXC;              // 196608
  unsigned short* Wouth = Winh + 3 * CC * CC;     // 65536
  unsigned short* Wm1h  = Wouth + CC * CC;        // 131072
  unsigned short* Wm2h  = Wm1h + 2 * CC * CC;     // 131072
  unsigned short* W1h   = Wm2h + 2 * CC * CC;     // 65536
  unsigned short* W1l   = W1h + CC * CC;          // 65536

  const int cvt_total = 9 * CC * CC;  // weights only
  k_cvt<<<(cvt_total + 255) / 256, 256, 0, stream>>>(
      Ws1, W1h, W1l, Win, Winh, Wout, Wouth, Wm1, Wm1h, Wm2, Wm2h);

  k_scorer<<<NN / 32, 256, 0, stream>>>(x, xh, W1h, W1l, bs1, Ws2, bs2, z);
  k_presel<<<BB, 512, 0, stream>>>(z, gum, ratio, k_per, codes, row2l);
  k_qkv<<<dim3(16, BB), 256, 0, stream>>>(xh, row2l, k_per, Winh, b_in, qh, kh, vh);
  k_attn<<<dim3(4, HH, BB), 256, 0, stream>>>(qh, kh, vh, k_per, ahb);
  k_opmlp<<<dim3(16, BB), 256, 0, stream>>>(ahb, codes, Wouth, bout, xh, ratio,
                                            Wm1h, bm1, Wm2h, bm2, out);
}